// Round 23
// baseline (7296.709 us; speedup 1.0000x reference)
//
#include <hip/hip_runtime.h>
#include <math.h>

// DummyRNN: h = tanh(x_t*w_ih + b_ih + W_hh@h + b_hh); y_t = W_out@h + b_out
//
// R24 = R22 (best: 5.00k us; 4-chain interleave, paired-ILP compute, batched
// publish/poll/load, XCD-local flag-split sync, W_hh bf16 in LDS) + TLP by
// CHAIN-SPLIT, not row-split: 512 threads, waves 0-3 run chains {0,1},
// waves 4-7 run chains {2,3}. Every wave keeps R22's exact shape (16 rows,
// pair-fused 2-chain compute, 64-wave fan-in, 64 flags/chain) -> barrier
// geometry unchanged; the second wave per SIMD (different chain-group)
// hides shfl/LDS/tanh stalls. R23's mistake (halved rows, doubled fan-in,
// doubled flag traffic) is avoided.

#define H      1024
#define TSTEPS 20480
#define BLOCK  512
#define WARM   64
#define WGSPC  16

typedef unsigned int uint;
typedef float f32x4 __attribute__((ext_vector_type(4)));

#define HDATA_BYTES ((size_t)64 * 2 * H * sizeof(float))   // 512 KB (coop)
#define CTRL_BYTES  ((size_t)24576)

__device__ __forceinline__ uint f2bf(float f) {            // fp32 -> bf16 RNE
    uint u = __float_as_uint(f);
    return (u + 0x7fffu + ((u >> 16) & 1u)) >> 16;
}

__global__ __launch_bounds__(BLOCK, 1)
void rnn_r24(const float* __restrict__ xs, const float* __restrict__ W_ih,
             const float* __restrict__ b_ih, const float* __restrict__ W_hh,
             const float* __restrict__ b_hh, const float* __restrict__ W_out,
             const float* __restrict__ b_out, float* __restrict__ y,
             float* __restrict__ hdata, uint* __restrict__ ctrl,
             int coop, int ilv, int chunk)
{
    const int tid    = threadIdx.x;
    const int bid    = blockIdx.x;
    const int wave   = tid >> 6;          // 0..7
    const int wg2    = (wave >> 2) & 1;   // chain-group within block
    const int wlocal = wave & 3;
    const int lane   = tid & 63;

    __shared__ uint  sW[64][512];         // 128 KB: 64 W_hh rows (bf16 pairs)
    __shared__ uint  sR[256];
    __shared__ int   sA[3];
    __shared__ float sY[8][2][8];         // [wave][klocal][it>>6] parked y

    uint* rcount = ctrl;                  // [0]
    uint* abortf = ctrl + 16;             // [16..31] per-GROUP abort flags
    uint* roster = ctrl + 64;             // [64..319]
    uint* flbase = ctrl + 1024;           // 64 chains x 64 per-wave flags

    int group, slot; bool fastm;
    if (coop) {
        uint xcc = __builtin_amdgcn_s_getreg(20 | (31 << 11)) & 7u; // HW_REG_XCC_ID
        if (tid == 0) {
            __hip_atomic_store(&roster[bid], xcc, __ATOMIC_RELAXED, __HIP_MEMORY_SCOPE_AGENT);
            asm volatile("s_waitcnt vmcnt(0)" ::: "memory");
            atomicAdd(rcount, 1u);
            while (__hip_atomic_load(rcount, __ATOMIC_RELAXED, __HIP_MEMORY_SCOPE_AGENT) < 256u)
                __builtin_amdgcn_s_sleep(2);
        }
        __syncthreads();
        if (tid < 256)
            sR[tid] = __hip_atomic_load(&roster[tid], __ATOMIC_RELAXED, __HIP_MEMORY_SCOPE_AGENT);
        __syncthreads();
        if (tid == 0) {
            int cnt[8] = {0,0,0,0,0,0,0,0};
            int myrank = 0, myx = 0;
            for (int b = 0; b < 256; ++b) {
                int x = (int)(sR[b] & 7u);
                int r = cnt[x]++;
                if (b == bid) { myrank = r; myx = x; }
            }
            int pre[9]; pre[0] = 0;
            for (int x = 0; x < 8; ++x) pre[x + 1] = pre[x] + cnt[x];
            int gidx = pre[myx] + myrank;
            int gr = gidx >> 4, sl = gidx & 15;
            int lo = gr << 4, hi = lo + 16, fok = 0;
            for (int x = 0; x < 8; ++x)
                if (pre[x] <= lo && hi <= pre[x + 1]) fok = 1;
            sA[0] = gr; sA[1] = sl; sA[2] = fok;
        }
        __syncthreads();
        group = sA[0]; slot = sA[1]; fastm = (sA[2] != 0);
    } else {
        group = bid / WGSPC; slot = bid % WGSPC; fastm = false;
    }

    uint* abortp = abortf + group;
    const int wic     = slot * 4 + wlocal;       // wave-in-chain 0..63
    const int rowbase = slot * 64 + wlocal * 16; // this wave's 16 rows
    const int rowwg   = slot * 64;
    const int ck0     = group * ilv;

    // this wave's two chains (k-indices within the group)
    const int kA = 2 * wg2, kB = 2 * wg2 + 1;
    const int cA = ck0 + kA, cB = ck0 + kB;
    const bool actA = (kA < ilv);
    const bool actB = (kB < ilv);
    const int warmA = (actA && cA) ? WARM : 0;
    const int warmB = (actB && cB) ? WARM : 0;
    const int nsA   = actA ? chunk + warmA : 0;
    const int nsB   = actB ? chunk + warmB : 0;
    const int t0A   = cA * chunk - warmA;
    const int t0B   = cB * chunk - warmB;

    // ---- one-time: stage the WG's 64 W_hh rows into LDS as bf16 pairs ----
    for (int idx = tid; idx < 64 * 512; idx += blockDim.x) {
        const int r = idx >> 9, p = idx & 511;
        const float2 w = *(const float2*)&W_hh[(size_t)(rowwg + r) * H + 2 * p];
        sW[r][p] = f2bf(w.x) | (f2bf(w.y) << 16);
    }
    __syncthreads();

    const int myrow = rowbase + (lane & 15);
    const float wih_s = W_ih[myrow];
    const float cb_s  = b_ih[myrow] + b_hh[myrow];

    f32x4 wo4[4];
    #pragma unroll
    for (int q = 0; q < 4; ++q)
        wo4[q] = *(const f32x4*)&W_out[256 * q + 4 * lane];
    const float bo = b_out[0];

    f32x4 hrvA[4] = {}, hrvB[4] = {};     // h[256q + 4l .. +3], h_0 = 0
    float lv0A = 0, lv1A = 0, lv0B = 0, lv1B = 0;
    uint  lfA = 0, lfB = 0;
    float xA = actA ? xs[t0A] : 0.0f;
    float xB = actB ? xs[t0B] : 0.0f;

    auto demote = [&]() {
        if (actA && lane < 16) {
            float* q0 = hdata + (size_t)cA * 2 * H + rowbase + (lane & 15);
            float* q1 = q0 + H;
            asm volatile("global_store_dword %0, %1, off sc0 sc1"
                         :: "v"(q0), "v"(lv0A) : "memory");
            asm volatile("global_store_dword %0, %1, off sc0 sc1"
                         :: "v"(q1), "v"(lv1A) : "memory");
        }
        if (actB && lane < 16) {
            float* q0 = hdata + (size_t)cB * 2 * H + rowbase + (lane & 15);
            float* q1 = q0 + H;
            asm volatile("global_store_dword %0, %1, off sc0 sc1"
                         :: "v"(q0), "v"(lv0B) : "memory");
            asm volatile("global_store_dword %0, %1, off sc0 sc1"
                         :: "v"(q1), "v"(lv1B) : "memory");
        }
        asm volatile("s_waitcnt vmcnt(0)" ::: "memory");
        if (lane == 0) {
            if (actA)
                asm volatile("global_store_dword %0, %1, off sc0 sc1"
                             :: "v"(flbase + cA * 64 + wic), "v"(lfA) : "memory");
            if (actB)
                asm volatile("global_store_dword %0, %1, off sc0 sc1"
                             :: "v"(flbase + cB * 64 + wic), "v"(lfB) : "memory");
            asm volatile("global_store_dword %0, %1, off sc0 sc1"
                         :: "v"(abortp), "v"(1u) : "memory");
        }
        asm volatile("s_waitcnt vmcnt(0)" ::: "memory");
        fastm = false;
    };

    auto abort_set = [&]() -> bool {
        uint ab;
        asm volatile("global_load_dword %0, %1, off sc0 sc1\n\ts_waitcnt vmcnt(0)"
                     : "=v"(ab) : "v"(abortp) : "memory");
        return __any(ab != 0u);
    };

    // single-chain poll+load (fallback + tails)
    auto poll_load_t = [&](int ck, int lt, float* out) {
        const uint* fa = flbase + ck * 64 + lane;
        const uint tt = (uint)lt;
        uint fails = 0;
        for (;;) {
            uint f;
            if (fastm)
                asm volatile("global_load_dword %0, %1, off sc0\n\ts_waitcnt vmcnt(0)"
                             : "=v"(f) : "v"(fa) : "memory");
            else
                asm volatile("global_load_dword %0, %1, off sc0 sc1\n\ts_waitcnt vmcnt(0)"
                             : "=v"(f) : "v"(fa) : "memory");
            if (__all(f >= tt)) break;
            ++fails;
            if (fastm) {
                if ((fails & 63u) == 0u) {
                    if (abort_set() || fails > 8192u) demote();
                }
                __builtin_amdgcn_s_sleep(1);
            } else {
                __builtin_amdgcn_s_sleep(8);
            }
        }
        const float* a = hdata + (size_t)ck * 2 * H + (size_t)(lt & 1) * H + 4 * lane;
        f32x4 A, B, C, D;
        if (fastm)
            asm volatile(
                "global_load_dwordx4 %0, %4, off sc0\n\t"
                "global_load_dwordx4 %1, %4, off offset:1024 sc0\n\t"
                "global_load_dwordx4 %2, %4, off offset:2048 sc0\n\t"
                "global_load_dwordx4 %3, %4, off offset:3072 sc0\n\t"
                "s_waitcnt vmcnt(0)"
                : "=&v"(A), "=&v"(B), "=&v"(C), "=&v"(D) : "v"(a) : "memory");
        else
            asm volatile(
                "global_load_dwordx4 %0, %4, off sc0 sc1\n\t"
                "global_load_dwordx4 %1, %4, off offset:1024 sc0 sc1\n\t"
                "global_load_dwordx4 %2, %4, off offset:2048 sc0 sc1\n\t"
                "global_load_dwordx4 %3, %4, off offset:3072 sc0 sc1\n\t"
                "s_waitcnt vmcnt(0)"
                : "=&v"(A), "=&v"(B), "=&v"(C), "=&v"(D) : "v"(a) : "memory");
        #pragma unroll
        for (int e = 0; e < 4; ++e) {
            out[e] = A[e]; out[4 + e] = B[e]; out[8 + e] = C[e]; out[12 + e] = D[e];
        }
    };

    // paired 16-row transpose-reduce (two trees interleaved stage-by-stage)
    auto reduce16x2 = [&](const float* za, const float* zb, float& ra, float& rb) {
        const bool b1 = (lane & 1) != 0;
        float sa0 = (b1 ? za[ 1] : za[ 0]) + __shfl_xor(b1 ? za[ 0] : za[ 1], 1);
        float sb0 = (b1 ? zb[ 1] : zb[ 0]) + __shfl_xor(b1 ? zb[ 0] : zb[ 1], 1);
        float sa1 = (b1 ? za[ 3] : za[ 2]) + __shfl_xor(b1 ? za[ 2] : za[ 3], 1);
        float sb1 = (b1 ? zb[ 3] : zb[ 2]) + __shfl_xor(b1 ? zb[ 2] : zb[ 3], 1);
        float sa2 = (b1 ? za[ 5] : za[ 4]) + __shfl_xor(b1 ? za[ 4] : za[ 5], 1);
        float sb2 = (b1 ? zb[ 5] : zb[ 4]) + __shfl_xor(b1 ? zb[ 4] : zb[ 5], 1);
        float sa3 = (b1 ? za[ 7] : za[ 6]) + __shfl_xor(b1 ? za[ 6] : za[ 7], 1);
        float sb3 = (b1 ? zb[ 7] : zb[ 6]) + __shfl_xor(b1 ? zb[ 6] : zb[ 7], 1);
        float sa4 = (b1 ? za[ 9] : za[ 8]) + __shfl_xor(b1 ? za[ 8] : za[ 9], 1);
        float sb4 = (b1 ? zb[ 9] : zb[ 8]) + __shfl_xor(b1 ? zb[ 8] : zb[ 9], 1);
        float sa5 = (b1 ? za[11] : za[10]) + __shfl_xor(b1 ? za[10] : za[11], 1);
        float sb5 = (b1 ? zb[11] : zb[10]) + __shfl_xor(b1 ? zb[10] : zb[11], 1);
        float sa6 = (b1 ? za[13] : za[12]) + __shfl_xor(b1 ? za[12] : za[13], 1);
        float sb6 = (b1 ? zb[13] : zb[12]) + __shfl_xor(b1 ? zb[12] : zb[13], 1);
        float sa7 = (b1 ? za[15] : za[14]) + __shfl_xor(b1 ? za[14] : za[15], 1);
        float sb7 = (b1 ? zb[15] : zb[14]) + __shfl_xor(b1 ? zb[14] : zb[15], 1);
        const bool b2 = (lane & 2) != 0;
        float ta0 = (b2 ? sa1 : sa0) + __shfl_xor(b2 ? sa0 : sa1, 2);
        float tb0 = (b2 ? sb1 : sb0) + __shfl_xor(b2 ? sb0 : sb1, 2);
        float ta1 = (b2 ? sa3 : sa2) + __shfl_xor(b2 ? sa2 : sa3, 2);
        float tb1 = (b2 ? sb3 : sb2) + __shfl_xor(b2 ? sb2 : sb3, 2);
        float ta2 = (b2 ? sa5 : sa4) + __shfl_xor(b2 ? sa4 : sa5, 2);
        float tb2 = (b2 ? sb5 : sb4) + __shfl_xor(b2 ? sb4 : sb5, 2);
        float ta3 = (b2 ? sa7 : sa6) + __shfl_xor(b2 ? sa6 : sa7, 2);
        float tb3 = (b2 ? sb7 : sb6) + __shfl_xor(b2 ? sb6 : sb7, 2);
        const bool b4 = (lane & 4) != 0;
        float ua0 = (b4 ? ta1 : ta0) + __shfl_xor(b4 ? ta0 : ta1, 4);
        float ub0 = (b4 ? tb1 : tb0) + __shfl_xor(b4 ? tb0 : tb1, 4);
        float ua1 = (b4 ? ta3 : ta2) + __shfl_xor(b4 ? ta2 : ta3, 4);
        float ub1 = (b4 ? tb3 : tb2) + __shfl_xor(b4 ? tb2 : tb3, 4);
        const bool b8 = (lane & 8) != 0;
        float va = (b8 ? ua1 : ua0) + __shfl_xor(b8 ? ua0 : ua1, 8);
        float vb = (b8 ? ub1 : ub0) + __shfl_xor(b8 ? ub0 : ub1, 8);
        va += __shfl_xor(va, 16);
        vb += __shfl_xor(vb, 16);
        va += __shfl_xor(va, 32);
        vb += __shfl_xor(vb, 32);
        ra = va; rb = vb;
    };

    const int nstep_max = chunk + ((ilv > 1 || group) ? WARM : 0);

    #pragma unroll 1
    for (int it = 0; it < nstep_max; ++it) {
        if (fastm && (it & 31) == 1) {
            if (abort_set()) demote();
        }

        const bool doA = actA && (it < nsA);
        const bool doB = actB && (it < nsB);

        // ---- phase 1: pair-fused compute of this wave's two chains ----
        float hvA = 0.0f, hvB = 0.0f;
        if (doA || doB) {
            float za[16], zb[16];
            #pragma unroll
            for (int r = 0; r < 16; ++r) {
                const uint2* wrow = (const uint2*)&sW[wlocal * 16 + r][2 * lane];
                float a = 0.0f, b = 0.0f;
                #pragma unroll
                for (int q = 0; q < 4; ++q) {
                    const uint2 u = wrow[q * 64];
                    const float w0 = __uint_as_float(u.x << 16);
                    const float w1 = __uint_as_float(u.x & 0xffff0000u);
                    const float w2 = __uint_as_float(u.y << 16);
                    const float w3 = __uint_as_float(u.y & 0xffff0000u);
                    a = fmaf(w0, hrvA[q][0], a);
                    b = fmaf(w0, hrvB[q][0], b);
                    a = fmaf(w1, hrvA[q][1], a);
                    b = fmaf(w1, hrvB[q][1], b);
                    a = fmaf(w2, hrvA[q][2], a);
                    b = fmaf(w2, hrvB[q][2], b);
                    a = fmaf(w3, hrvA[q][3], a);
                    b = fmaf(w3, hrvB[q][3], b);
                }
                za[r] = a; zb[r] = b;
            }
            float zra, zrb;
            reduce16x2(za, zb, zra, zrb);
            const float va = fmaf(xA, wih_s, cb_s + zra);
            const float vb = fmaf(xB, wih_s, cb_s + zrb);
            hvA = tanhf(va);
            hvB = tanhf(vb);
        }

        // ---- phase 2: publish (h stores -> ONE vmcnt -> flag stores) ----
        const int par = (it + 1) & 1;
        if (doA && lane < 16) {
            float* dst = hdata + (size_t)(cA * 2 + par) * H + rowbase + (lane & 15);
            if (fastm)
                asm volatile("global_store_dword %0, %1, off"
                             :: "v"(dst), "v"(hvA) : "memory");
            else
                asm volatile("global_store_dword %0, %1, off sc0 sc1"
                             :: "v"(dst), "v"(hvA) : "memory");
        }
        if (doB && lane < 16) {
            float* dst = hdata + (size_t)(cB * 2 + par) * H + rowbase + (lane & 15);
            if (fastm)
                asm volatile("global_store_dword %0, %1, off"
                             :: "v"(dst), "v"(hvB) : "memory");
            else
                asm volatile("global_store_dword %0, %1, off sc0 sc1"
                             :: "v"(dst), "v"(hvB) : "memory");
        }
        asm volatile("s_waitcnt vmcnt(0)" ::: "memory");
        {
            const uint nf = (uint)(it + 1);
            if (lane == 0) {
                if (doA) {
                    if (fastm)
                        asm volatile("global_store_dword %0, %1, off"
                                     :: "v"(flbase + cA * 64 + wic), "v"(nf) : "memory");
                    else
                        asm volatile("global_store_dword %0, %1, off sc0 sc1"
                                     :: "v"(flbase + cA * 64 + wic), "v"(nf) : "memory");
                }
                if (doB) {
                    if (fastm)
                        asm volatile("global_store_dword %0, %1, off"
                                     :: "v"(flbase + cB * 64 + wic), "v"(nf) : "memory");
                    else
                        asm volatile("global_store_dword %0, %1, off sc0 sc1"
                                     :: "v"(flbase + cB * 64 + wic), "v"(nf) : "memory");
                }
            }
            if (doA) { if (par == 0) lv0A = hvA; else lv1A = hvA; lfA = nf; }
            if (doB) { if (par == 0) lv0B = hvB; else lv1B = hvB; lfB = nf; }
        }

        // ---- y duty (uses h_it = hrv, park in LDS) ----
        if (doA && wic == (it & 63) && it >= warmA + 1) {
            float acc = 0.0f;
            #pragma unroll
            for (int q = 0; q < 4; ++q) {
                acc = fmaf(wo4[q][0], hrvA[q][0], acc);
                acc = fmaf(wo4[q][1], hrvA[q][1], acc);
                acc = fmaf(wo4[q][2], hrvA[q][2], acc);
                acc = fmaf(wo4[q][3], hrvA[q][3], acc);
            }
            #pragma unroll
            for (int off = 32; off > 0; off >>= 1)
                acc += __shfl_xor(acc, off);
            if (lane == 0) {
                if (coop) sY[wave][0][it >> 6] = acc + bo;
                else      y[t0A + it - 1] = acc + bo;
            }
        }
        if (doB && wic == (it & 63) && it >= warmB + 1) {
            float acc = 0.0f;
            #pragma unroll
            for (int q = 0; q < 4; ++q) {
                acc = fmaf(wo4[q][0], hrvB[q][0], acc);
                acc = fmaf(wo4[q][1], hrvB[q][1], acc);
                acc = fmaf(wo4[q][2], hrvB[q][2], acc);
                acc = fmaf(wo4[q][3], hrvB[q][3], acc);
            }
            #pragma unroll
            for (int off = 32; off > 0; off >>= 1)
                acc += __shfl_xor(acc, off);
            if (lane == 0) {
                if (coop) sY[wave][1][it >> 6] = acc + bo;
                else      y[t0B + it - 1] = acc + bo;
            }
        }
        if (doA && it + 1 < nsA) xA = xs[t0A + it + 1];
        if (doB && it + 1 < nsB) xB = xs[t0B + it + 1];

        // ---- phases 3+4: combined 2-chain poll (1 RT) + load (1 RT) ----
        if (ilv == 4) {
            const uint tgA = (it + 1 < nsA) ? (uint)(it + 1) : 0u;
            const uint tgB = (it + 1 < nsB) ? (uint)(it + 1) : 0u;
            if (tgA | tgB) {
                const uint* fa = flbase + cA * 64 + lane;   // cB = cA+1 -> +256B
                uint fails = 0;
                for (;;) {
                    uint f0, f1;
                    if (fastm)
                        asm volatile(
                            "global_load_dword %0, %2, off sc0\n\t"
                            "global_load_dword %1, %2, off offset:256 sc0\n\t"
                            "s_waitcnt vmcnt(0)"
                            : "=&v"(f0), "=&v"(f1) : "v"(fa) : "memory");
                    else
                        asm volatile(
                            "global_load_dword %0, %2, off sc0 sc1\n\t"
                            "global_load_dword %1, %2, off offset:256 sc0 sc1\n\t"
                            "s_waitcnt vmcnt(0)"
                            : "=&v"(f0), "=&v"(f1) : "v"(fa) : "memory");
                    if (__all((f0 >= tgA) & (f1 >= tgB))) break;
                    ++fails;
                    if (fastm) {
                        if ((fails & 63u) == 0u) {
                            if (abort_set() || fails > 8192u) demote();
                        }
                        __builtin_amdgcn_s_sleep(1);
                    } else {
                        __builtin_amdgcn_s_sleep(8);
                    }
                }
                const float* a0p = hdata + (size_t)(cA * 2 + par) * H + 4 * lane;
                const float* a1p = a0p + 2 * H;             // chain cB
                if (fastm)
                    asm volatile(
                        "global_load_dwordx4 %0, %8, off sc0\n\t"
                        "global_load_dwordx4 %1, %8, off offset:1024 sc0\n\t"
                        "global_load_dwordx4 %2, %8, off offset:2048 sc0\n\t"
                        "global_load_dwordx4 %3, %8, off offset:3072 sc0\n\t"
                        "global_load_dwordx4 %4, %9, off sc0\n\t"
                        "global_load_dwordx4 %5, %9, off offset:1024 sc0\n\t"
                        "global_load_dwordx4 %6, %9, off offset:2048 sc0\n\t"
                        "global_load_dwordx4 %7, %9, off offset:3072 sc0\n\t"
                        "s_waitcnt vmcnt(0)"
                        : "=&v"(hrvA[0]), "=&v"(hrvA[1]), "=&v"(hrvA[2]), "=&v"(hrvA[3]),
                          "=&v"(hrvB[0]), "=&v"(hrvB[1]), "=&v"(hrvB[2]), "=&v"(hrvB[3])
                        : "v"(a0p), "v"(a1p) : "memory");
                else
                    asm volatile(
                        "global_load_dwordx4 %0, %8, off sc0 sc1\n\t"
                        "global_load_dwordx4 %1, %8, off offset:1024 sc0 sc1\n\t"
                        "global_load_dwordx4 %2, %8, off offset:2048 sc0 sc1\n\t"
                        "global_load_dwordx4 %3, %8, off offset:3072 sc0 sc1\n\t"
                        "global_load_dwordx4 %4, %9, off sc0 sc1\n\t"
                        "global_load_dwordx4 %5, %9, off offset:1024 sc0 sc1\n\t"
                        "global_load_dwordx4 %6, %9, off offset:2048 sc0 sc1\n\t"
                        "global_load_dwordx4 %7, %9, off offset:3072 sc0 sc1\n\t"
                        "s_waitcnt vmcnt(0)"
                        : "=&v"(hrvA[0]), "=&v"(hrvA[1]), "=&v"(hrvA[2]), "=&v"(hrvA[3]),
                          "=&v"(hrvB[0]), "=&v"(hrvB[1]), "=&v"(hrvB[2]), "=&v"(hrvB[3])
                        : "v"(a0p), "v"(a1p) : "memory");
            }
        } else {
            // fallback (ilv==1): only chain cA of wg2==0 waves is active
            if (actA && it + 1 < nsA) {
                float out[16];
                poll_load_t(cA, it + 1, out);
                #pragma unroll
                for (int q = 0; q < 4; ++q)
                    #pragma unroll
                    for (int e = 0; e < 4; ++e)
                        hrvA[q][e] = out[4 * q + e];
            }
        }
    }

    // ---- flush parked y (coop): it = 64*kk + wic -> y[t0+it-1] ----
    if (coop && lane == 0) {
        #pragma unroll 1
        for (int kk = 0; kk < 8; ++kk) {
            const int it = (kk << 6) + wic;
            if (actA && it >= warmA + 1 && it < nsA)
                y[t0A + it - 1] = sY[wave][0][kk];
            if (actB && it >= warmB + 1 && it < nsB)
                y[t0B + it - 1] = sY[wave][1][kk];
        }
    }

    // tail: y[t0+nstep-1] from h_nstep (slot 0, wave 0 per group)
    if (slot == 0 && wave == 0) {
        #pragma unroll
        for (int k = 0; k < 4; ++k) {
            if (k >= ilv) continue;
            const int ck = ck0 + k;
            const int w_ = ck ? WARM : 0;
            const int ns_ = chunk + w_;
            const int t0_ = ck * chunk - w_;
            float out[16];
            poll_load_t(ck, ns_, out);
            float acc = 0.0f;
            #pragma unroll
            for (int q = 0; q < 4; ++q) {
                acc = fmaf(wo4[q][0], out[4 * q + 0], acc);
                acc = fmaf(wo4[q][1], out[4 * q + 1], acc);
                acc = fmaf(wo4[q][2], out[4 * q + 2], acc);
                acc = fmaf(wo4[q][3], out[4 * q + 3], acc);
            }
            #pragma unroll
            for (int off = 32; off > 0; off >>= 1)
                acc += __shfl_xor(acc, off);
            if (lane == 0) y[t0_ + ns_ - 1] = acc + bo;
        }
    }
}

extern "C" void kernel_launch(void* const* d_in, const int* in_sizes, int n_in,
                              void* d_out, int out_size, void* d_ws, size_t ws_size,
                              hipStream_t stream) {
    const float* xs    = (const float*)d_in[0];
    const float* W_ih  = (const float*)d_in[1];
    const float* b_ih  = (const float*)d_in[2];
    const float* W_hh  = (const float*)d_in[3];
    const float* b_hh  = (const float*)d_in[4];
    const float* W_out = (const float*)d_in[5];
    const float* b_out = (const float*)d_in[6];
    float* y = (float*)d_out;

    const size_t need = HDATA_BYTES + CTRL_BYTES;
    int use_coop = (ws_size >= need) ? 1 : 0;

    float* hdata = (float*)d_ws;
    uint*  ctrl  = (uint*)((char*)d_ws +
                           (use_coop ? HDATA_BYTES
                                     : (size_t)4 * 2 * H * sizeof(float)));

    (void)hipMemsetAsync(d_ws, 0,
                         use_coop ? need
                                  : (size_t)4 * 2 * H * sizeof(float) + CTRL_BYTES,
                         stream);

    if (use_coop) {
        int coop = 1, ilv = 4, chunk = TSTEPS / 64;          // 64 chains x 320
        void* args[] = { (void*)&xs, (void*)&W_ih, (void*)&b_ih, (void*)&W_hh,
                         (void*)&b_hh, (void*)&W_out, (void*)&b_out, (void*)&y,
                         (void*)&hdata, (void*)&ctrl,
                         (void*)&coop, (void*)&ilv, (void*)&chunk };
        hipError_t e = hipLaunchCooperativeKernel((const void*)rnn_r24,
                                                  dim3(256), dim3(BLOCK),
                                                  args, 0, stream);
        if (e != hipSuccess) use_coop = 0;
    }
    if (!use_coop) {
        rnn_r24<<<4 * WGSPC, BLOCK, 0, stream>>>(
            xs, W_ih, b_ih, W_hh, b_hh, W_out, b_out, y,
            hdata, ctrl, 0, 1, TSTEPS / 4);
    }
}